// Round 6
// baseline (1933.785 us; speedup 1.0000x reference)
//
#include <hip/hip_runtime.h>
#include <hip/hip_bf16.h>
#include <math.h>

// Problem constants (DeepSeek-V2 MLA, B=1, S=2048)
#define S_    2048
#define H_    32
#define HID_  5120
#define QL_   1536
#define QH_   192     // DN + DR
#define DN_   128
#define DR_   64
#define DV_   128
#define KVL_  512

typedef short  bf8x  __attribute__((ext_vector_type(8)));   // 8 bf16 = 4 VGPR (MFMA A/B frag)
typedef short  bf4x  __attribute__((ext_vector_type(4)));
typedef float  f32x4 __attribute__((ext_vector_type(4)));

#define MFMA16(a, b, c) __builtin_amdgcn_mfma_f32_16x16x32_bf16((a), (b), (c), 0, 0, 0)

// Markidis split: v ~= hi + lo, hi/lo bf16. Compiler emits v_cvt_pk_bf16_f32.
__device__ __forceinline__ void split2(float v, short& h, short& l) {
  const __hip_bfloat16 hb = __float2bfloat16(v);
  h = (short)__bfloat16_as_short(hb);
  l = (short)__bfloat16_as_short(__float2bfloat16(v - __bfloat162float(hb)));
}

// ---------------------------------------------------------------------------
// Split-bf16 MFMA GEMM: C[M,N] = A[M,K](f32) @ B[K,N](f32, row-major, ldb).
// Both operands split to hi/lo bf16 IN-KERNEL during LDS staging; 3 MFMAs per
// product (hh + hl + lh), fp32 acc => ~1e-5 rel. 128x128 tile, BK=32,
// 4 waves (2x2), 64x64/wave (4x4 frags of 16x16x32).
// A frag: lane l holds A[l%16][8*(l/16)+j]; B frag: Bt[l%16][8*(l/16)+j];
// C/D:    col = l&15, row = (l>>4)*4 + r   [measured m89].
// B staging: thread t reads B[k0+kb+kk][n0+nn] (nn=t&127 -> 64-lane coalesced
// scalar loads), writes k-contiguous bf8x to sB[nn][kb..] (20-bank row stride
// -> 8 lanes span all 32 banks: conflict-free).
// MODE 0: C row-major [M][ldc].
// MODE 1 (kvb projection): per output col c (N=8192): h=c>>8, j=c&255;
//   j<128  -> C[row*ldc + h*128 + j]            (k_nope, row-major)
//   j>=128 -> C2[(h*128 + j-128)*S_ + row]      (V transposed, float4 store)
// ~175 VGPR estimate -> (256,2) pins 2 waves/SIMD (2 blocks/CU) spill-free.
// ---------------------------------------------------------------------------
template <int MODE>
__global__ __launch_bounds__(256, 2) void gemm_bf16s(
    const float* __restrict__ A, const float* __restrict__ B,
    float* __restrict__ C, float* __restrict__ C2,
    int M, int N, int K, int lda, int ldb, int ldc)
{
  // [128][40] bf16: row stride 80 B (20 banks) -> b128 frag reads cover all
  // 32 banks uniformly (2-way over 16 rows = free, m136).
  __shared__ short sAh[128][40], sAl[128][40], sBh[128][40], sBl[128][40];

  const int t  = threadIdx.x;
  const int l  = t & 63;
  const int wv = t >> 6;
  const int wm = wv >> 1, wn = wv & 1;
  const int m0 = blockIdx.y * 128, n0 = blockIdx.x * 128;

  const int sr = t >> 3;            // A staging row base (0..31)
  const int sc = (t & 7) * 4;       // A staging k-col (0..28)
  const int nn = t & 127;           // B staging n-row (0..127)
  const int kb = (t >> 7) * 16;     // B staging k-base (0/16)
  const bool nok = (n0 + nn) < N;

  f32x4 acc[4][4] = {};

  float4 pa[4];
  float  pb[16];

  // ---- prefetch K-tile 0 ----
  #pragma unroll
  for (int w = 0; w < 4; ++w)
    pa[w] = *(const float4*)&A[(size_t)(m0 + sr + w * 32) * lda + sc];
  #pragma unroll
  for (int kk = 0; kk < 16; ++kk)
    pb[kk] = nok ? B[(size_t)(kb + kk) * ldb + n0 + nn] : 0.f;

  for (int k0 = 0; k0 < K; k0 += 32) {
    __syncthreads();   // previous tile's readers done

    // ---- regs -> LDS (split f32 -> hi/lo bf16) ----
    #pragma unroll
    for (int w = 0; w < 4; ++w) {
      const int r = sr + w * 32;
      const float vv[4] = {pa[w].x, pa[w].y, pa[w].z, pa[w].w};
      bf4x h4, l4;
      #pragma unroll
      for (int i = 0; i < 4; ++i) { short hh, ll; split2(vv[i], hh, ll); h4[i] = hh; l4[i] = ll; }
      *(bf4x*)&sAh[r][sc] = h4;
      *(bf4x*)&sAl[r][sc] = l4;
    }
    {
      bf8x hb0, lb0, hb1, lb1;
      #pragma unroll
      for (int j = 0; j < 8; ++j) { short hh, ll; split2(pb[j], hh, ll); hb0[j] = hh; lb0[j] = ll; }
      #pragma unroll
      for (int j = 0; j < 8; ++j) { short hh, ll; split2(pb[8 + j], hh, ll); hb1[j] = hh; lb1[j] = ll; }
      *(bf8x*)&sBh[nn][kb]     = hb0;
      *(bf8x*)&sBl[nn][kb]     = lb0;
      *(bf8x*)&sBh[nn][kb + 8] = hb1;
      *(bf8x*)&sBl[nn][kb + 8] = lb1;
    }
    __syncthreads();

    // ---- prefetch next tile (latency hides under 48 MFMAs) ----
    if (k0 + 32 < K) {
      #pragma unroll
      for (int w = 0; w < 4; ++w)
        pa[w] = *(const float4*)&A[(size_t)(m0 + sr + w * 32) * lda + k0 + 32 + sc];
      #pragma unroll
      for (int kk = 0; kk < 16; ++kk)
        pb[kk] = nok ? B[(size_t)(k0 + 32 + kb + kk) * ldb + n0 + nn] : 0.f;
    }

    // ---- fragments + 48 MFMAs ----
    const int fr = l & 15;
    const int kg = (l >> 4) * 8;
    bf8x ah[4], al[4], bh[4], bl[4];
    #pragma unroll
    for (int mi = 0; mi < 4; ++mi) {
      const int row = wm * 64 + mi * 16 + fr;
      ah[mi] = *(const bf8x*)&sAh[row][kg];
      al[mi] = *(const bf8x*)&sAl[row][kg];
    }
    #pragma unroll
    for (int ni = 0; ni < 4; ++ni) {
      const int row = wn * 64 + ni * 16 + fr;
      bh[ni] = *(const bf8x*)&sBh[row][kg];
      bl[ni] = *(const bf8x*)&sBl[row][kg];
    }
    #pragma unroll
    for (int mi = 0; mi < 4; ++mi)
      #pragma unroll
      for (int ni = 0; ni < 4; ++ni) {
        acc[mi][ni] = MFMA16(ah[mi], bh[ni], acc[mi][ni]);
        acc[mi][ni] = MFMA16(ah[mi], bl[ni], acc[mi][ni]);
        acc[mi][ni] = MFMA16(al[mi], bh[ni], acc[mi][ni]);
      }
  }

  // ---- store ----
  #pragma unroll
  for (int mi = 0; mi < 4; ++mi) {
    #pragma unroll
    for (int ni = 0; ni < 4; ++ni) {
      const int rg = m0 + wm * 64 + mi * 16 + ((l >> 4) * 4);
      const int cg = n0 + wn * 64 + ni * 16 + (l & 15);
      if (MODE == 0) {
        if (cg < N) {
          #pragma unroll
          for (int r = 0; r < 4; ++r)
            C[(size_t)(rg + r) * ldc + cg] = acc[mi][ni][r];
        }
      } else {
        const int hh = cg >> 8, j = cg & 255;
        if (j < 128) {
          #pragma unroll
          for (int r = 0; r < 4; ++r)
            C[(size_t)(rg + r) * ldc + hh * 128 + j] = acc[mi][ni][r];
        } else {
          *(f32x4*)&C2[(size_t)(hh * 128 + (j - 128)) * S_ + rg] = acc[mi][ni];
        }
      }
    }
  }
}

// ---------------------------------------------------------------------------
// In-place RMSNorm over rows.
// ---------------------------------------------------------------------------
__global__ __launch_bounds__(256) void rmsnorm_k(
    float* __restrict__ x, const float* __restrict__ w, int W, int stride)
{
  __shared__ float red[4];
  const int row = blockIdx.x;
  float* xr = x + (size_t)row * stride;
  float s = 0.f;
  for (int i = threadIdx.x; i < W; i += 256) { float v = xr[i]; s += v * v; }
  #pragma unroll
  for (int off = 32; off >= 1; off >>= 1) s += __shfl_xor(s, off, 64);
  const int lane = threadIdx.x & 63, wid = threadIdx.x >> 6;
  if (lane == 0) red[wid] = s;
  __syncthreads();
  const float tot = red[0] + red[1] + red[2] + red[3];
  const float r = rsqrtf(tot / (float)W + 1e-6f);
  for (int i = threadIdx.x; i < W; i += 256) xr[i] = xr[i] * r * w[i];
}

// ---------------------------------------------------------------------------
// RoPE (fp32 angles like reference).
// ---------------------------------------------------------------------------
__device__ __forceinline__ void rope_pair(float* x, int d, int s)
{
  const float invf = (float)exp((double)d * -0.28782313662425574); // ln(1e4)/32
  const float ang  = (float)s * invf;
  float sn, cs;
  sincosf(ang, &sn, &cs);
  const float x0 = x[d], x1 = x[d + 32];
  x[d]      = x0 * cs - x1 * sn;
  x[d + 32] = x1 * cs + x0 * sn;
}

__global__ __launch_bounds__(256) void rope_q_k(float* __restrict__ q)
{
  const int idx = blockIdx.x * 256 + threadIdx.x;       // S*H*32 pairs
  if (idx >= S_ * H_ * 32) return;
  const int d = idx & 31;
  const int h = (idx >> 5) & 31;
  const int s = idx >> 10;
  rope_pair(q + (size_t)s * (H_ * QH_) + h * QH_ + DN_, d, s);
}

__global__ __launch_bounds__(256) void rope_k_k(float* __restrict__ ckv)
{
  const int idx = blockIdx.x * 256 + threadIdx.x;       // S*32 pairs
  if (idx >= S_ * 32) return;
  const int d = idx & 31;
  const int s = idx >> 5;
  rope_pair(ckv + (size_t)s * (KVL_ + DR_) + KVL_, d, s);
}

// ---------------------------------------------------------------------------
// MFMA flash attention (split-bf16, causal). Block = (64 q-rows, 1 head),
// 256 thr = 4 waves; wave w owns q-rows q0+16w..+15. KVBLK=32.
// Q scaled+split held in registers as A-frags (staged via K buffer in 2
// halves). K[32][192] and V^T[128][32] staged+split per tile; P split and
// passed through LDS. 3-term split on QK^T and PV => ~1e-5 rel accuracy.
// LDS 55 KB -> 2 blocks/CU (2 waves/SIMD).
// ---------------------------------------------------------------------------
__global__ __launch_bounds__(256, 2) void attn_mfma(
    const float* __restrict__ q,      // [S][H*192] (roped)
    const float* __restrict__ knope,  // [S][H*128]
    const float* __restrict__ ckv,    // [S][576], roped k_pe at col 512
    const float* __restrict__ vT,     // [H*128][S]
    float* __restrict__ attnb)        // [S][H*128]
{
  __shared__ short sKh[32][200], sKl[32][200];   // 25.6 KB (also Q staging)
  __shared__ short sVh[128][40], sVl[128][40];   // 20.5 KB
  __shared__ short sPh[64][40],  sPl[64][40];    // 10.2 KB

  const int t   = threadIdx.x;
  const int l   = t & 63;
  const int w   = t >> 6;
  const int fr  = l & 15;
  const int kg8 = (l >> 4) * 8;
  const int q0  = blockIdx.x * 64;
  const int h   = blockIdx.y;
  const float scale = 0.07216878364870322f;   // 192^-0.5

  // ---- phase A: Q -> registers (scaled, split), via sK buffer, 2 halves ----
  bf8x qh[6], ql[6];
  #pragma unroll
  for (int half = 0; half < 2; ++half) {
    {
      const int r  = t >> 3;                 // 0..31
      const int c0 = (t & 7) * 24;
      const float* src = q + (size_t)(q0 + half * 32 + r) * (H_ * QH_)
                           + (size_t)h * QH_ + c0;
      #pragma unroll
      for (int j = 0; j < 6; ++j) {
        const float4 v = *(const float4*)(src + 4 * j);
        const float vv[4] = {v.x * scale, v.y * scale, v.z * scale, v.w * scale};
        bf4x h4, l4;
        #pragma unroll
        for (int i = 0; i < 4; ++i) { short hh, ll; split2(vv[i], hh, ll); h4[i] = hh; l4[i] = ll; }
        *(bf4x*)&sKh[r][c0 + 4 * j] = h4;
        *(bf4x*)&sKl[r][c0 + 4 * j] = l4;
      }
    }
    __syncthreads();
    if ((w >> 1) == half) {
      const int lr = (w & 1) * 16 + fr;
      #pragma unroll
      for (int ks = 0; ks < 6; ++ks) {
        qh[ks] = *(const bf8x*)&sKh[lr][ks * 32 + kg8];
        ql[ks] = *(const bf8x*)&sKl[lr][ks * 32 + kg8];
      }
    }
    __syncthreads();   // half-0 readers done before half-1 overwrites
  }

  f32x4 O[8] = {};
  float mrow[4] = {-1e30f, -1e30f, -1e30f, -1e30f};
  float lrow[4] = {0.f, 0.f, 0.f, 0.f};

  const int nt = (q0 + 95) / 32;     // ceil((q0+64)/32) kv tiles
  for (int tt = 0; tt < nt; ++tt) {
    const int t0 = tt * 32;
    __syncthreads();   // prev tile's K/V/P readers done

    // ---- stage K tile (32 x 192 f32 -> split bf16) ----
    {
      const int r  = t >> 3;
      const int c0 = (t & 7) * 24;
      #pragma unroll
      for (int j = 0; j < 6; ++j) {
        const int c = c0 + 4 * j;
        float4 v;
        if (c < 128)
          v = *(const float4*)&knope[(size_t)(t0 + r) * (H_ * DN_) + h * DN_ + c];
        else
          v = *(const float4*)&ckv[(size_t)(t0 + r) * (KVL_ + DR_) + KVL_ + (c - 128)];
        const float vv[4] = {v.x, v.y, v.z, v.w};
        bf4x h4, l4;
        #pragma unroll
        for (int i = 0; i < 4; ++i) { short hh, ll; split2(vv[i], hh, ll); h4[i] = hh; l4[i] = ll; }
        *(bf4x*)&sKh[r][c] = h4;
        *(bf4x*)&sKl[r][c] = l4;
      }
    }
    // ---- stage V^T tile (128 vcols x 32 kv) ----
    {
      const int vr = t >> 1;                  // 0..127
      const int c0 = (t & 1) * 16;
      #pragma unroll
      for (int j = 0; j < 4; ++j) {
        const float4 v = *(const float4*)&vT[(size_t)(h * DV_ + vr) * S_ + t0 + c0 + 4 * j];
        const float vv[4] = {v.x, v.y, v.z, v.w};
        bf4x h4, l4;
        #pragma unroll
        for (int i = 0; i < 4; ++i) { short hh, ll; split2(vv[i], hh, ll); h4[i] = hh; l4[i] = ll; }
        *(bf4x*)&sVh[vr][c0 + 4 * j] = h4;
        *(bf4x*)&sVl[vr][c0 + 4 * j] = l4;
      }
    }
    __syncthreads();

    // ---- QK^T: 16q x 32kv per wave, K-dim 192 (6 ksteps x 3 mfma x 2 ni) ----
    f32x4 s0 = {}, s1 = {};
    #pragma unroll
    for (int ks = 0; ks < 6; ++ks) {
      const int kc = ks * 32 + kg8;
      bf8x b0h = *(const bf8x*)&sKh[fr][kc];
      bf8x b0l = *(const bf8x*)&sKl[fr][kc];
      bf8x b1h = *(const bf8x*)&sKh[16 + fr][kc];
      bf8x b1l = *(const bf8x*)&sKl[16 + fr][kc];
      s0 = MFMA16(qh[ks], b0h, s0);
      s0 = MFMA16(qh[ks], b0l, s0);
      s0 = MFMA16(ql[ks], b0h, s0);
      s1 = MFMA16(qh[ks], b1h, s1);
      s1 = MFMA16(qh[ks], b1l, s1);
      s1 = MFMA16(ql[ks], b1h, s1);
    }

    // ---- online softmax on C-layout (col=fr=kv, rows=(l>>4)*4+r=q) ----
    #pragma unroll
    for (int r = 0; r < 4; ++r) {
      const int rl = (l >> 4) * 4 + r;         // row within wave's 16
      const int qr = q0 + w * 16 + rl;         // global q row
      float v0 = s0[r]; if (t0 + fr > qr)      v0 = -1e30f;
      float v1 = s1[r]; if (t0 + 16 + fr > qr) v1 = -1e30f;
      float pm = fmaxf(v0, v1);
      pm = fmaxf(pm, __shfl_xor(pm, 1, 64));
      pm = fmaxf(pm, __shfl_xor(pm, 2, 64));
      pm = fmaxf(pm, __shfl_xor(pm, 4, 64));
      pm = fmaxf(pm, __shfl_xor(pm, 8, 64));
      const float mn    = fmaxf(mrow[r], pm);
      const float alpha = __expf(mrow[r] - mn);
      const float p0 = __expf(v0 - mn);
      const float p1 = __expf(v1 - mn);
      float rs = p0 + p1;
      rs += __shfl_xor(rs, 1, 64);
      rs += __shfl_xor(rs, 2, 64);
      rs += __shfl_xor(rs, 4, 64);
      rs += __shfl_xor(rs, 8, 64);
      lrow[r] = lrow[r] * alpha + rs;
      mrow[r] = mn;
      #pragma unroll
      for (int n = 0; n < 8; ++n) O[n][r] *= alpha;
      // P -> LDS (split bf16)
      const int prow = w * 16 + rl;
      short h0, l0, h1, l1;
      split2(p0, h0, l0);
      split2(p1, h1, l1);
      sPh[prow][fr]      = h0;
      sPl[prow][fr]      = l0;
      sPh[prow][16 + fr] = h1;
      sPl[prow][16 + fr] = l1;
    }
    __syncthreads();   // P ready

    // ---- PV: O[16q x 128v] += P[16q x 32kv] @ V[32kv x 128v] ----
    const bf8x pa = *(const bf8x*)&sPh[w * 16 + fr][kg8];
    const bf8x pb = *(const bf8x*)&sPl[w * 16 + fr][kg8];
    #pragma unroll
    for (int n = 0; n < 8; ++n) {
      bf8x vh = *(const bf8x*)&sVh[n * 16 + fr][kg8];
      bf8x vl = *(const bf8x*)&sVl[n * 16 + fr][kg8];
      O[n] = MFMA16(pa, vh, O[n]);
      O[n] = MFMA16(pa, vl, O[n]);
      O[n] = MFMA16(pb, vh, O[n]);
    }
  }

  // ---- epilogue: O / l ----
  #pragma unroll
  for (int r = 0; r < 4; ++r) {
    const int qr  = q0 + w * 16 + (l >> 4) * 4 + r;
    const float inv = 1.0f / lrow[r];
    #pragma unroll
    for (int n = 0; n < 8; ++n)
      attnb[(size_t)qr * (H_ * DV_) + h * DV_ + n * 16 + fr] = O[n][r] * inv;
  }
}

// ---------------------------------------------------------------------------
extern "C" void kernel_launch(void* const* d_in, const int* in_sizes, int n_in,
                              void* d_out, int out_size, void* d_ws, size_t ws_size,
                              hipStream_t stream)
{
  const float* hidden   = (const float*)d_in[0];
  const float* w_qa     = (const float*)d_in[1];
  const float* qa_ln_w  = (const float*)d_in[2];
  const float* w_qb     = (const float*)d_in[3];
  const float* w_kva    = (const float*)d_in[4];
  const float* kva_ln_w = (const float*)d_in[5];
  const float* w_kvb    = (const float*)d_in[6];
  const float* w_o      = (const float*)d_in[7];
  float* out = (float*)d_out;

  // ---- workspace layout (all f32; attnb aliases qa: qa dead after qb-gemm,
  //      attnb born at attention). Total 38,928,384 floats = 148.5 MiB. ----
  const size_t n_qbuf  = (size_t)S_ * (H_ * QH_);     // 12.58M
  const size_t n_knope = (size_t)S_ * (H_ * DN_);     //  8.39M
  const size_t n_vT    = (size_t)H_ * DV_ * S_;       //  8.39M
  const size_t n_ckv   = (size_t)S_ * (KVL_ + DR_);   //  1.18M
  const size_t n_shared= (size_t)S_ * (H_ * DV_);     //  8.39M (>= qa 3.15M)
  const size_t need = (n_qbuf + n_knope + n_vT + n_ckv + n_shared) * sizeof(float);
  if (ws_size < need) return;   // diagnostic: fail validation instead of faulting

  float* ws    = (float*)d_ws;
  float* qbuf  = ws;
  float* knope = qbuf  + n_qbuf;
  float* vT    = knope + n_knope;
  float* ckv   = vT    + n_vT;
  float* qa    = ckv   + n_ckv;    // shared region
  float* attnb = qa;               // alias (disjoint lifetimes)

  const dim3 blk(256);

  // qa = hidden @ w_qa
  gemm_bf16s<0><<<dim3(QL_/128, S_/128), blk, 0, stream>>>(
      hidden, w_qa, qa, nullptr, S_, QL_, HID_, HID_, QL_, QL_);
  // ckv = hidden @ w_kva (N=576, guarded)
  gemm_bf16s<0><<<dim3((KVL_+DR_+127)/128, S_/128), blk, 0, stream>>>(
      hidden, w_kva, ckv, nullptr, S_, KVL_+DR_, HID_, HID_, KVL_+DR_, KVL_+DR_);
  // RMSNorms (in-place)
  rmsnorm_k<<<S_, 256, 0, stream>>>(qa, qa_ln_w, QL_, QL_);
  rmsnorm_k<<<S_, 256, 0, stream>>>(ckv, kva_ln_w, KVL_, KVL_+DR_);
  // q = qa_n @ w_qb
  gemm_bf16s<0><<<dim3(H_*QH_/128, S_/128), blk, 0, stream>>>(
      qa, w_qb, qbuf, nullptr, S_, H_*QH_, QL_, QL_, H_*QH_, H_*QH_);
  // kv = ckv_n @ w_kvb -> knope (row-major) + vT (transposed V)
  gemm_bf16s<1><<<dim3(H_*(DN_+DV_)/128, S_/128), blk, 0, stream>>>(
      ckv, w_kvb, knope, vT, S_, H_*(DN_+DV_), KVL_, KVL_+DR_, H_*(DN_+DV_), H_*DN_);
  // RoPE (in-place)
  rope_q_k<<<(S_*H_*32 + 255)/256, 256, 0, stream>>>(qbuf);
  rope_k_k<<<(S_*32 + 255)/256, 256, 0, stream>>>(ckv);
  // MFMA flash attention
  attn_mfma<<<dim3(S_/64, H_), blk, 0, stream>>>(qbuf, knope, ckv, vT, attnb);
  // out = attn @ w_o
  gemm_bf16s<0><<<dim3(HID_/128, S_/128), blk, 0, stream>>>(
      attnb, w_o, out, nullptr, S_, HID_, H_*DV_, H_*DV_, HID_, HID_);
}